// Round 3
// baseline (890.540 us; speedup 1.0000x reference)
//
#include <hip/hip_runtime.h>

#define C 32
#define WNODE 128          // nodes per bucket
#define WSHIFT 7
#define CHUNK 4096         // edges per sort-phase block
#define NT 256

// ---- phase 1: per-block histogram of dst buckets ----
__global__ void bucket_hist(const int* __restrict__ dst, int* __restrict__ cnt,
                            int E, int nbuck) {
    extern __shared__ int lcnt[];
    for (int i = threadIdx.x; i < nbuck; i += NT) lcnt[i] = 0;
    __syncthreads();
    int base = blockIdx.x * CHUNK;
    for (int k = 0; k < CHUNK; k += NT) {
        int e = base + k + threadIdx.x;
        if (e < E) atomicAdd(&lcnt[dst[e] >> WSHIFT], 1);
    }
    __syncthreads();
    int* row = cnt + (size_t)blockIdx.x * nbuck;
    for (int i = threadIdx.x; i < nbuck; i += NT) row[i] = lcnt[i];
}

// ---- phase 2a: per-bucket column scan (cnt[g][b] -> exclusive prefix over g),
//      btot[b] = total edges in bucket b. Coalesced across b. ----
__global__ void col_scan(int* __restrict__ cnt, int* __restrict__ btot,
                         int G, int nbuck) {
    int b = blockIdx.x * blockDim.x + threadIdx.x;
    if (b >= nbuck) return;
    int run = 0;
    for (int g = 0; g < G; ++g) {
        int* p = cnt + (size_t)g * nbuck + b;
        int c = *p; *p = run; run += c;
    }
    btot[b] = run;
}

// ---- phase 2b: exclusive scan of bucket totals (nbuck <= 1024) ----
__global__ void bucket_scan(const int* __restrict__ btot, int* __restrict__ bbase,
                            int nbuck, int E) {
    __shared__ int s[1024];
    int t = threadIdx.x;
    int v = (t < nbuck) ? btot[t] : 0;
    s[t] = v;
    __syncthreads();
    for (int off = 1; off < 1024; off <<= 1) {
        int u = (t >= off) ? s[t - off] : 0;
        __syncthreads();
        s[t] += u;
        __syncthreads();
    }
    if (t < nbuck) bbase[t] = s[t] - v;
    if (t == 0) bbase[nbuck] = E;
}

// ---- phase 3: scatter packed (src | dres<<17) into bucket-grouped order.
//      Each block owns an exclusive contiguous sub-range per bucket -> LDS
//      cursors only, no global atomics. ----
__global__ void bucket_scatter(const int* __restrict__ src, const int* __restrict__ dst,
                               const int* __restrict__ cnt, const int* __restrict__ bbase,
                               int* __restrict__ pk, int E, int nbuck) {
    extern __shared__ int cur[];
    const int* row = cnt + (size_t)blockIdx.x * nbuck;
    for (int i = threadIdx.x; i < nbuck; i += NT)
        cur[i] = bbase[i] + row[i];
    __syncthreads();
    int base = blockIdx.x * CHUNK;
    for (int k = 0; k < CHUNK; k += NT) {
        int e = base + k + threadIdx.x;
        if (e < E) {
            int d = dst[e];
            int b = d >> WSHIFT;
            int pos = atomicAdd(&cur[b], 1);
            pk[pos] = src[e] | ((d & (WNODE - 1)) << 17);
        }
    }
}

// ---- matvec 1: t1 = deg*x - A@x, LDS-tile push per bucket ----
__global__ __launch_bounds__(NT) void matvec1(
        const float* __restrict__ x, const int* __restrict__ pk,
        const int* __restrict__ bbase, float* __restrict__ t1, int N) {
    __shared__ float tile[WNODE * C];
    __shared__ int   dtile[WNODE];
    int tid = threadIdx.x;
    for (int i = tid; i < WNODE * C; i += NT) tile[i] = 0.f;
    for (int i = tid; i < WNODE; i += NT) dtile[i] = 0;
    __syncthreads();
    int b = blockIdx.x;
    int rs = bbase[b], re = bbase[b + 1];
    int ch = tid & 31;
    int slot = tid >> 5;                  // 8 half-wave slots per block
    int j = rs + slot;
    for (; j + 8 < re; j += 16) {         // 2-deep unroll: both loads in flight
        int p0 = pk[j], p1 = pk[j + 8];
        float v0 = x[(size_t)(p0 & 0x1FFFF) * C + ch];
        float v1 = x[(size_t)(p1 & 0x1FFFF) * C + ch];
        atomicAdd(&tile[(p0 >> 17) * C + ch], v0);
        atomicAdd(&tile[(p1 >> 17) * C + ch], v1);
        if (ch == 0) { atomicAdd(&dtile[p0 >> 17], 1); atomicAdd(&dtile[p1 >> 17], 1); }
    }
    if (j < re) {
        int p0 = pk[j];
        float v0 = x[(size_t)(p0 & 0x1FFFF) * C + ch];
        atomicAdd(&tile[(p0 >> 17) * C + ch], v0);
        if (ch == 0) atomicAdd(&dtile[p0 >> 17], 1);
    }
    __syncthreads();
    int d0 = b << WSHIFT;
    for (int r = tid >> 5; r < WNODE; r += 8) {
        int n = d0 + r;
        if (n < N) {
            size_t o = (size_t)n * C + ch;
            t1[o] = (float)dtile[r] * x[o] - tile[r * C + ch];
        }
    }
}

// ---- matvec 2 + fused final: y = w0*x + w1*t1 + w2*(deg*t1 - A@t1) ----
__global__ __launch_bounds__(NT) void matvec2(
        const float* __restrict__ x, const float* __restrict__ t1v,
        const int* __restrict__ pk, const int* __restrict__ bbase,
        const float* __restrict__ wts, float* __restrict__ y, int N) {
    __shared__ float tile[WNODE * C];
    __shared__ int   dtile[WNODE];
    int tid = threadIdx.x;
    for (int i = tid; i < WNODE * C; i += NT) tile[i] = 0.f;
    for (int i = tid; i < WNODE; i += NT) dtile[i] = 0;
    __syncthreads();
    int b = blockIdx.x;
    int rs = bbase[b], re = bbase[b + 1];
    int ch = tid & 31;
    int slot = tid >> 5;
    int j = rs + slot;
    for (; j + 8 < re; j += 16) {
        int p0 = pk[j], p1 = pk[j + 8];
        float v0 = t1v[(size_t)(p0 & 0x1FFFF) * C + ch];
        float v1 = t1v[(size_t)(p1 & 0x1FFFF) * C + ch];
        atomicAdd(&tile[(p0 >> 17) * C + ch], v0);
        atomicAdd(&tile[(p1 >> 17) * C + ch], v1);
        if (ch == 0) { atomicAdd(&dtile[p0 >> 17], 1); atomicAdd(&dtile[p1 >> 17], 1); }
    }
    if (j < re) {
        int p0 = pk[j];
        float v0 = t1v[(size_t)(p0 & 0x1FFFF) * C + ch];
        atomicAdd(&tile[(p0 >> 17) * C + ch], v0);
        if (ch == 0) atomicAdd(&dtile[p0 >> 17], 1);
    }
    __syncthreads();
    float w0 = wts[0], w1 = wts[1], w2 = wts[2];
    int d0 = b << WSHIFT;
    for (int r = tid >> 5; r < WNODE; r += 8) {
        int n = d0 + r;
        if (n < N) {
            size_t o = (size_t)n * C + ch;
            float tv = t1v[o];
            y[o] = w0 * x[o] + w1 * tv + w2 * ((float)dtile[r] * tv - tile[r * C + ch]);
        }
    }
}

extern "C" void kernel_launch(void* const* d_in, const int* in_sizes, int n_in,
                              void* d_out, int out_size, void* d_ws, size_t ws_size,
                              hipStream_t stream) {
    const float* x    = (const float*)d_in[0];
    const float* wts  = (const float*)d_in[1];
    const int*   esrc = (const int*)d_in[2];
    const int*   edst = (const int*)d_in[3];
    float*       y    = (float*)d_out;

    const int N = in_sizes[0] / C;                 // 100000
    const int E = in_sizes[2];                     // 1600000
    const int nbuck = (N + WNODE - 1) >> WSHIFT;   // 782 (<= 1024 required)
    const int G = (E + CHUNK - 1) / CHUNK;         // 391

    // ws: cnt[G*nbuck] | btot[nbuck] | bbase[nbuck+1] | pk[E] | t1[N*C]  (~21 MB)
    char* p = (char*)d_ws;
    auto align16 = [](size_t s) { return (s + 15) & ~(size_t)15; };
    int* cnt   = (int*)p; p += align16((size_t)G * nbuck * 4);
    int* btot  = (int*)p; p += align16((size_t)nbuck * 4);
    int* bbase = (int*)p; p += align16((size_t)(nbuck + 1) * 4);
    int* pk    = (int*)p; p += align16((size_t)E * 4);
    float* t1  = (float*)p;

    const size_t lds_buck = (size_t)nbuck * 4;

    bucket_hist   <<<G, NT, lds_buck, stream>>>(edst, cnt, E, nbuck);
    col_scan      <<<(nbuck + NT - 1) / NT, NT, 0, stream>>>(cnt, btot, G, nbuck);
    bucket_scan   <<<1, 1024, 0, stream>>>(btot, bbase, nbuck, E);
    bucket_scatter<<<G, NT, lds_buck, stream>>>(esrc, edst, cnt, bbase, pk, E, nbuck);
    matvec1       <<<nbuck, NT, 0, stream>>>(x, pk, bbase, t1, N);
    matvec2       <<<nbuck, NT, 0, stream>>>(x, t1, pk, bbase, wts, y, N);
}

// Round 4
// 206.012 us; speedup vs baseline: 4.3228x; 4.3228x over previous
//
#include <hip/hip_runtime.h>

#define C 32
#define NT 256
#define BSH 8              // 256 nodes per bucket
#define BNODE 256
#define CAPC 5632          // per-bucket capacity (mean ~4096, +24 sigma)
#define SRCMASK 0x1FFFF    // 17 bits for src (N < 131072)

// cursor[b] = b*CAPC
__global__ void init_cursor(int* __restrict__ cursor, int nbuck) {
    int i = blockIdx.x * blockDim.x + threadIdx.x;
    if (i < nbuck) cursor[i] = i * CAPC;
}

// Phase A: bucketize edges by dst>>8 into per-bucket regions of pk.
// Per block: LDS hist of its chunk -> one global atomicAdd per bucket to
// reserve a contiguous slice -> scatter packed (src | dres<<17).
__global__ __launch_bounds__(NT) void phaseA(const int* __restrict__ src,
                                             const int* __restrict__ dst,
                                             int* __restrict__ cursor,
                                             int* __restrict__ pk,
                                             int E, int nbuck, int chunk) {
    extern __shared__ int l[];          // lcnt[nbuck] | lcur[nbuck]
    int* lcnt = l;
    int* lcur = l + nbuck;
    int tid = threadIdx.x;
    for (int i = tid; i < nbuck; i += NT) lcnt[i] = 0;
    __syncthreads();
    int base = blockIdx.x * chunk;
    int end  = min(base + chunk, E);
    for (int e = base + tid; e < end; e += NT)
        atomicAdd(&lcnt[dst[e] >> BSH], 1);
    __syncthreads();
    for (int i = tid; i < nbuck; i += NT) {
        int c = lcnt[i];
        lcur[i] = c ? atomicAdd(&cursor[i], c) : 0;
    }
    __syncthreads();
    for (int e = base + tid; e < end; e += NT) {
        int d = dst[e];
        int b = d >> BSH;
        int pos = atomicAdd(&lcur[b], 1);
        pk[pos] = src[e] | ((d & (BNODE - 1)) << 17);
    }
}

// Phase B: per-bucket counting sort, in place. Stages entries in LDS,
// 256-counter hist + scan, writes row_start/ideg (coalesced), scatters
// plain src back into the bucket's own global window (L2-absorbed).
__global__ __launch_bounds__(NT) void phaseB(int* __restrict__ pk,
                                             const int* __restrict__ cursor,
                                             int* __restrict__ row_start,
                                             int* __restrict__ ideg,
                                             int N) {
    __shared__ int ent[CAPC];
    __shared__ int h[BNODE];
    __shared__ int s[BNODE];
    __shared__ int cur[BNODE];
    int b = blockIdx.x;
    int tid = threadIdx.x;
    int base = b * CAPC;
    int cnt = min(cursor[b] - base, CAPC);
    for (int i = tid; i < cnt; i += NT) ent[i] = pk[base + i];
    h[tid] = 0;
    __syncthreads();
    for (int i = tid; i < cnt; i += NT) atomicAdd(&h[ent[i] >> 17], 1);
    __syncthreads();
    int v = h[tid];
    s[tid] = v;
    __syncthreads();
    for (int off = 1; off < BNODE; off <<= 1) {
        int u = (tid >= off) ? s[tid - off] : 0;
        __syncthreads();
        s[tid] += u;
        __syncthreads();
    }
    int exc = s[tid] - v;               // exclusive prefix within bucket
    int n = (b << BSH) + tid;
    if (n < N) {
        row_start[n] = base + exc;
        ideg[n] = v;
    }
    cur[tid] = exc;
    __syncthreads();
    for (int i = tid; i < cnt; i += NT) {
        int en = ent[i];
        int pos = atomicAdd(&cur[en >> 17], 1);
        pk[base + pos] = en & SRCMASK;
    }
}

// Gather matvec 1: t1 = deg*x - A@x. Half-wave (32 lanes = 32 channels)
// per node; 4-deep unroll => 8 independent row loads in flight per wave.
__global__ __launch_bounds__(NT) void gather1(const float* __restrict__ x,
                                              const int* __restrict__ pk,
                                              const int* __restrict__ row_start,
                                              const int* __restrict__ ideg,
                                              float* __restrict__ t1, int N) {
    int g = blockIdx.x * blockDim.x + threadIdx.x;
    int n = g >> 5;
    if (n >= N) return;
    int ch = g & 31;
    int rs = row_start[n];
    int dg = ideg[n];
    int re = rs + dg;
    float a0 = 0.f, a1 = 0.f, a2 = 0.f, a3 = 0.f;
    int j = rs;
    for (; j + 3 < re; j += 4) {
        int s0 = pk[j], s1 = pk[j + 1], s2 = pk[j + 2], s3 = pk[j + 3];
        a0 += x[(size_t)s0 * C + ch];
        a1 += x[(size_t)s1 * C + ch];
        a2 += x[(size_t)s2 * C + ch];
        a3 += x[(size_t)s3 * C + ch];
    }
    for (; j < re; ++j) a0 += x[(size_t)pk[j] * C + ch];
    float acc = (a0 + a1) + (a2 + a3);
    size_t o = (size_t)n * C + ch;
    t1[o] = (float)dg * x[o] - acc;
}

// Gather matvec 2 + fused final: y = w0*x + w1*t1 + w2*(deg*t1 - A@t1)
__global__ __launch_bounds__(NT) void gather2(const float* __restrict__ x,
                                              const float* __restrict__ t1,
                                              const int* __restrict__ pk,
                                              const int* __restrict__ row_start,
                                              const int* __restrict__ ideg,
                                              const float* __restrict__ wts,
                                              float* __restrict__ y, int N) {
    int g = blockIdx.x * blockDim.x + threadIdx.x;
    int n = g >> 5;
    if (n >= N) return;
    int ch = g & 31;
    int rs = row_start[n];
    int dg = ideg[n];
    int re = rs + dg;
    float a0 = 0.f, a1 = 0.f, a2 = 0.f, a3 = 0.f;
    int j = rs;
    for (; j + 3 < re; j += 4) {
        int s0 = pk[j], s1 = pk[j + 1], s2 = pk[j + 2], s3 = pk[j + 3];
        a0 += t1[(size_t)s0 * C + ch];
        a1 += t1[(size_t)s1 * C + ch];
        a2 += t1[(size_t)s2 * C + ch];
        a3 += t1[(size_t)s3 * C + ch];
    }
    for (; j < re; ++j) a0 += t1[(size_t)pk[j] * C + ch];
    float acc = (a0 + a1) + (a2 + a3);
    size_t o = (size_t)n * C + ch;
    float tv = t1[o];
    y[o] = wts[0] * x[o] + wts[1] * tv + wts[2] * ((float)dg * tv - acc);
}

extern "C" void kernel_launch(void* const* d_in, const int* in_sizes, int n_in,
                              void* d_out, int out_size, void* d_ws, size_t ws_size,
                              hipStream_t stream) {
    const float* x    = (const float*)d_in[0];
    const float* wts  = (const float*)d_in[1];
    const int*   esrc = (const int*)d_in[2];
    const int*   edst = (const int*)d_in[3];
    float*       y    = (float*)d_out;

    const int N = in_sizes[0] / C;                 // 100000
    const int E = in_sizes[2];                     // 1600000
    const int nbuck = (N + BNODE - 1) >> BSH;      // 391

    // ws: cursor[nbuck] | row_start[N] | ideg[N] | pk[nbuck*CAPC] | t1[N*C]
    char* p = (char*)d_ws;
    auto align16 = [](size_t s) { return (s + 15) & ~(size_t)15; };
    int* cursor    = (int*)p; p += align16((size_t)nbuck * 4);
    int* row_start = (int*)p; p += align16((size_t)N * 4);
    int* ideg      = (int*)p; p += align16((size_t)N * 4);
    int* pk        = (int*)p; p += align16((size_t)nbuck * CAPC * 4);
    float* t1      = (float*)p;

    init_cursor<<<(nbuck + NT - 1) / NT, NT, 0, stream>>>(cursor, nbuck);

    const int ABLK = 256;
    const int chunk = (E + ABLK - 1) / ABLK;
    const size_t lds_a = (size_t)nbuck * 2 * 4;
    phaseA<<<ABLK, NT, lds_a, stream>>>(esrc, edst, cursor, pk, E, nbuck, chunk);
    phaseB<<<nbuck, NT, 0, stream>>>(pk, cursor, row_start, ideg, N);

    const int gblocks = ((size_t)N * 32 + NT - 1) / NT;   // half-wave per node
    gather1<<<gblocks, NT, 0, stream>>>(x, pk, row_start, ideg, t1, N);
    gather2<<<gblocks, NT, 0, stream>>>(x, t1, pk, row_start, ideg, wts, y, N);
}

// Round 5
// 174.884 us; speedup vs baseline: 5.0922x; 1.1780x over previous
//
#include <hip/hip_runtime.h>

#define C 32
#define NT 256
#define BSH 8              // 256 nodes per bucket
#define BNODE 256
#define CAPC 5632          // per-bucket capacity (mean 4096, +24 sigma)
#define SRCMASK 0x1FFFF

__device__ __forceinline__ unsigned int f2bf(float f) {
    unsigned int u = __float_as_uint(f);
    return (u + 0x7FFFu + ((u >> 16) & 1u)) >> 16;   // RNE to bf16
}
__device__ __forceinline__ float bflo(unsigned int u) { return __uint_as_float(u << 16); }
__device__ __forceinline__ float bfhi(unsigned int u) { return __uint_as_float(u & 0xFFFF0000u); }

__global__ void init_cursor(int* __restrict__ cursor, int nbuck) {
    int i = blockIdx.x * blockDim.x + threadIdx.x;
    if (i < nbuck) cursor[i] = i * CAPC;
}

// x fp32 -> packed bf16 pairs (one uint = 2 channels)
__global__ void cvt_kernel(const float2* __restrict__ x2, unsigned int* __restrict__ xb, int n2) {
    int i = blockIdx.x * blockDim.x + threadIdx.x;
    if (i >= n2) return;
    float2 v = x2[i];
    xb[i] = f2bf(v.x) | (f2bf(v.y) << 16);
}

// Phase A: bucketize by dst>>8 via per-block LDS hist + one global reservation
// atomic per bucket. 1024 threads/block for latency hiding.
__global__ __launch_bounds__(1024) void phaseA(const int* __restrict__ src,
                                               const int* __restrict__ dst,
                                               int* __restrict__ cursor,
                                               int* __restrict__ pk,
                                               int E, int nbuck, int chunk) {
    extern __shared__ int l[];          // lcnt[nbuck] | lcur[nbuck]
    int* lcnt = l;
    int* lcur = l + nbuck;
    int tid = threadIdx.x;
    for (int i = tid; i < nbuck; i += 1024) lcnt[i] = 0;
    __syncthreads();
    int base = blockIdx.x * chunk;
    int end  = min(base + chunk, E);
    for (int e = base + tid; e < end; e += 1024)
        atomicAdd(&lcnt[dst[e] >> BSH], 1);
    __syncthreads();
    for (int i = tid; i < nbuck; i += 1024) {
        int c = lcnt[i];
        lcur[i] = c ? atomicAdd(&cursor[i], c) : 0;
    }
    __syncthreads();
    for (int e = base + tid; e < end; e += 1024) {
        int d = dst[e];
        int b = d >> BSH;
        int pos = atomicAdd(&lcur[b], 1);
        pk[pos] = src[e] | ((d & (BNODE - 1)) << 17);
    }
}

// Phase B: per-bucket counting sort in place (512 threads).
__global__ __launch_bounds__(512) void phaseB(int* __restrict__ pk,
                                              const int* __restrict__ cursor,
                                              int* __restrict__ row_start,
                                              int* __restrict__ ideg, int N) {
    __shared__ int ent[CAPC];
    __shared__ int h[BNODE];
    __shared__ int s[BNODE];
    __shared__ int cur[BNODE];
    int b = blockIdx.x;
    int tid = threadIdx.x;
    int base = b * CAPC;
    int cnt = min(cursor[b] - base, CAPC);
    for (int i = tid; i < cnt; i += 512) ent[i] = pk[base + i];
    if (tid < BNODE) h[tid] = 0;
    __syncthreads();
    for (int i = tid; i < cnt; i += 512) atomicAdd(&h[ent[i] >> 17], 1);
    __syncthreads();
    int v = 0;
    if (tid < BNODE) { v = h[tid]; s[tid] = v; }
    __syncthreads();
    for (int off = 1; off < BNODE; off <<= 1) {
        int u = 0;
        if (tid < BNODE && tid >= off) u = s[tid - off];
        __syncthreads();
        if (tid < BNODE) s[tid] += u;
        __syncthreads();
    }
    if (tid < BNODE) {
        int exc = s[tid] - v;
        int n = (b << BSH) + tid;
        if (n < N) { row_start[n] = base + exc; ideg[n] = v; }
        cur[tid] = exc;
    }
    __syncthreads();
    for (int i = tid; i < cnt; i += 512) {
        int en = ent[i];
        int pos = atomicAdd(&cur[en >> 17], 1);
        pk[base + pos] = en & SRCMASK;
    }
}

// ---- bf16-row gathers: 16 lanes per node, each lane = 2 channels ----
__global__ __launch_bounds__(NT) void gather1_bf(const float* __restrict__ x,
        const unsigned int* __restrict__ xb, const int* __restrict__ pk,
        const int* __restrict__ row_start, const int* __restrict__ ideg,
        float* __restrict__ t1, unsigned int* __restrict__ t1b, int N) {
    int g = blockIdx.x * blockDim.x + threadIdx.x;
    int n = g >> 4;
    if (n >= N) return;
    int l = g & 15;
    int rs = row_start[n];
    int dg = ideg[n];
    int re = rs + dg;
    float ax0=0,ay0=0,ax1=0,ay1=0,ax2=0,ay2=0,ax3=0,ay3=0;
    int j = rs;
    for (; j + 3 < re; j += 4) {
        int s0 = pk[j], s1 = pk[j+1], s2 = pk[j+2], s3 = pk[j+3];
        unsigned int u0 = xb[s0*16 + l], u1 = xb[s1*16 + l];
        unsigned int u2 = xb[s2*16 + l], u3 = xb[s3*16 + l];
        ax0 += bflo(u0); ay0 += bfhi(u0);
        ax1 += bflo(u1); ay1 += bfhi(u1);
        ax2 += bflo(u2); ay2 += bfhi(u2);
        ax3 += bflo(u3); ay3 += bfhi(u3);
    }
    for (; j < re; ++j) { unsigned int u = xb[pk[j]*16 + l]; ax0 += bflo(u); ay0 += bfhi(u); }
    float sx = (ax0+ax1)+(ax2+ax3), sy = (ay0+ay1)+(ay2+ay3);
    size_t o = (size_t)n * C + l * 2;
    float2 xv = *(const float2*)(x + o);
    float fdg = (float)dg;
    float2 tv; tv.x = fdg * xv.x - sx; tv.y = fdg * xv.y - sy;
    *(float2*)(t1 + o) = tv;
    t1b[n*16 + l] = f2bf(tv.x) | (f2bf(tv.y) << 16);
}

__global__ __launch_bounds__(NT) void gather2_bf(const float* __restrict__ x,
        const float* __restrict__ t1, const unsigned int* __restrict__ t1b,
        const int* __restrict__ pk, const int* __restrict__ row_start,
        const int* __restrict__ ideg, const float* __restrict__ wts,
        float* __restrict__ y, int N) {
    int g = blockIdx.x * blockDim.x + threadIdx.x;
    int n = g >> 4;
    if (n >= N) return;
    int l = g & 15;
    int rs = row_start[n];
    int dg = ideg[n];
    int re = rs + dg;
    float ax0=0,ay0=0,ax1=0,ay1=0,ax2=0,ay2=0,ax3=0,ay3=0;
    int j = rs;
    for (; j + 3 < re; j += 4) {
        int s0 = pk[j], s1 = pk[j+1], s2 = pk[j+2], s3 = pk[j+3];
        unsigned int u0 = t1b[s0*16 + l], u1 = t1b[s1*16 + l];
        unsigned int u2 = t1b[s2*16 + l], u3 = t1b[s3*16 + l];
        ax0 += bflo(u0); ay0 += bfhi(u0);
        ax1 += bflo(u1); ay1 += bfhi(u1);
        ax2 += bflo(u2); ay2 += bfhi(u2);
        ax3 += bflo(u3); ay3 += bfhi(u3);
    }
    for (; j < re; ++j) { unsigned int u = t1b[pk[j]*16 + l]; ax0 += bflo(u); ay0 += bfhi(u); }
    float sx = (ax0+ax1)+(ax2+ax3), sy = (ay0+ay1)+(ay2+ay3);
    size_t o = (size_t)n * C + l * 2;
    float2 xv = *(const float2*)(x + o);
    float2 tv = *(const float2*)(t1 + o);
    float w0 = wts[0], w1 = wts[1], w2 = wts[2];
    float fdg = (float)dg;
    float2 r;
    r.x = w0 * xv.x + w1 * tv.x + w2 * (fdg * tv.x - sx);
    r.y = w0 * xv.y + w1 * tv.y + w2 * (fdg * tv.y - sy);
    *(float2*)(y + o) = r;
}

// ---- fp32 fallback gathers (R4-proven) used only if ws_size is too small ----
__global__ __launch_bounds__(NT) void gather1_f32(const float* __restrict__ x,
        const int* __restrict__ pk, const int* __restrict__ row_start,
        const int* __restrict__ ideg, float* __restrict__ t1, int N) {
    int g = blockIdx.x * blockDim.x + threadIdx.x;
    int n = g >> 5;
    if (n >= N) return;
    int ch = g & 31;
    int rs = row_start[n], dg = ideg[n], re = rs + dg;
    float a0=0,a1=0,a2=0,a3=0;
    int j = rs;
    for (; j + 3 < re; j += 4) {
        a0 += x[(size_t)pk[j]*C + ch];   a1 += x[(size_t)pk[j+1]*C + ch];
        a2 += x[(size_t)pk[j+2]*C + ch]; a3 += x[(size_t)pk[j+3]*C + ch];
    }
    for (; j < re; ++j) a0 += x[(size_t)pk[j]*C + ch];
    size_t o = (size_t)n*C + ch;
    t1[o] = (float)dg * x[o] - ((a0+a1)+(a2+a3));
}
__global__ __launch_bounds__(NT) void gather2_f32(const float* __restrict__ x,
        const float* __restrict__ t1, const int* __restrict__ pk,
        const int* __restrict__ row_start, const int* __restrict__ ideg,
        const float* __restrict__ wts, float* __restrict__ y, int N) {
    int g = blockIdx.x * blockDim.x + threadIdx.x;
    int n = g >> 5;
    if (n >= N) return;
    int ch = g & 31;
    int rs = row_start[n], dg = ideg[n], re = rs + dg;
    float a0=0,a1=0,a2=0,a3=0;
    int j = rs;
    for (; j + 3 < re; j += 4) {
        a0 += t1[(size_t)pk[j]*C + ch];   a1 += t1[(size_t)pk[j+1]*C + ch];
        a2 += t1[(size_t)pk[j+2]*C + ch]; a3 += t1[(size_t)pk[j+3]*C + ch];
    }
    for (; j < re; ++j) a0 += t1[(size_t)pk[j]*C + ch];
    size_t o = (size_t)n*C + ch;
    float tv = t1[o];
    y[o] = wts[0]*x[o] + wts[1]*tv + wts[2]*((float)dg*tv - ((a0+a1)+(a2+a3)));
}

extern "C" void kernel_launch(void* const* d_in, const int* in_sizes, int n_in,
                              void* d_out, int out_size, void* d_ws, size_t ws_size,
                              hipStream_t stream) {
    const float* x    = (const float*)d_in[0];
    const float* wts  = (const float*)d_in[1];
    const int*   esrc = (const int*)d_in[2];
    const int*   edst = (const int*)d_in[3];
    float*       y    = (float*)d_out;

    const int N = in_sizes[0] / C;                 // 100000
    const int E = in_sizes[2];                     // 1600000
    const int nbuck = (N + BNODE - 1) >> BSH;      // 391
    const int nc = N * C;

    char* p = (char*)d_ws;
    auto align16 = [](size_t s) { return (s + 15) & ~(size_t)15; };
    int* cursor    = (int*)p; p += align16((size_t)nbuck * 4);
    int* row_start = (int*)p; p += align16((size_t)N * 4);
    int* ideg      = (int*)p; p += align16((size_t)N * 4);
    int* pk        = (int*)p; p += align16((size_t)nbuck * CAPC * 4);
    float* t1      = (float*)p; p += align16((size_t)nc * 4);
    unsigned int* xb  = (unsigned int*)p; p += align16((size_t)nc * 2);
    unsigned int* t1b = (unsigned int*)p; p += align16((size_t)nc * 2);
    bool bf_ok = (size_t)(p - (char*)d_ws) <= ws_size;

    init_cursor<<<(nbuck + NT - 1) / NT, NT, 0, stream>>>(cursor, nbuck);

    const int ABLK = 256;
    const int chunk = (E + ABLK - 1) / ABLK;
    const size_t lds_a = (size_t)nbuck * 2 * 4;
    phaseA<<<ABLK, 1024, lds_a, stream>>>(esrc, edst, cursor, pk, E, nbuck, chunk);
    phaseB<<<nbuck, 512, 0, stream>>>(pk, cursor, row_start, ideg, N);

    if (bf_ok) {
        const int n2 = nc / 2;
        cvt_kernel<<<(n2 + NT - 1) / NT, NT, 0, stream>>>((const float2*)x, xb, n2);
        const int gblocks = ((size_t)N * 16 + NT - 1) / NT;
        gather1_bf<<<gblocks, NT, 0, stream>>>(x, xb, pk, row_start, ideg, t1, t1b, N);
        gather2_bf<<<gblocks, NT, 0, stream>>>(x, t1, t1b, pk, row_start, ideg, wts, y, N);
    } else {
        const int gblocks = ((size_t)N * 32 + NT - 1) / NT;
        gather1_f32<<<gblocks, NT, 0, stream>>>(x, pk, row_start, ideg, t1, N);
        gather2_f32<<<gblocks, NT, 0, stream>>>(x, t1, pk, row_start, ideg, wts, y, N);
    }
}